// Round 1
// baseline (3719.487 us; speedup 1.0000x reference)
//
#include <hip/hip_runtime.h>

#define BB 8
#define NN 32768
#define KK 128
#define DD 64
#define TAU 1.0f
#define ITERS 10
#define EPSV 1e-8f

// ---- d_out layout (floats) ----
#define G_SZ   ((size_t)BB * NN * KK)          // 33554432
#define PI_OFF (G_SZ)                          // B*K
#define XY_OFF (PI_OFF + (size_t)BB * KK)      // B*K*3
#define NF_OUT (XY_OFF + (size_t)BB * KK * 3)  // B*K*D

// ---- d_ws layout (floats) ----
#define CT_OFF 0        // transformed centers: B*K*4  {2cx/t, 2cy/t, 2cz/t, -|c|^2/t}
#define ACC_OFF 4096    // accumulators: B*K*4  {sum gx, sum gy, sum gz, sum g}
#define SS_OFF 8192     // s_sum per batch: B
#define NF_OFF 8448     // node_feats accumulator: B*K*D

// ================= prep: s_sum, init centers, zero acc =================
__global__ __launch_bounds__(256) void prep_kernel(const float* __restrict__ xyz,
                                                   const float* __restrict__ sc,
                                                   float* __restrict__ ws) {
    int b = blockIdx.x, tid = threadIdx.x;
    const float* sb = sc + (size_t)b * NN;
    float sum = 0.f;
    for (int i = tid; i < NN; i += 256) sum += sb[i];
    #pragma unroll
    for (int off = 32; off; off >>= 1) sum += __shfl_down(sum, off);
    __shared__ float red[4];
    if ((tid & 63) == 0) red[tid >> 6] = sum;
    __syncthreads();
    if (tid == 0) ws[SS_OFF + b] = red[0] + red[1] + red[2] + red[3] + EPSV;
    if (tid < KK) {
        const float* X = xyz + (size_t)b * 3 * NN;
        int n = tid * (NN / KK);
        float cx = X[n], cy = X[NN + n], cz = X[2 * NN + n];
        float4* cT = (float4*)(ws + CT_OFF);
        cT[b * KK + tid] = make_float4(2.f * cx / TAU, 2.f * cy / TAU, 2.f * cz / TAU,
                                       -(cx * cx + cy * cy + cz * cz) / TAU);
    }
    for (int i = tid; i < KK * 4; i += 256) ws[ACC_OFF + b * KK * 4 + i] = 0.f;
}

// ================= assign: softmax + accumulate (2 pts/thread) =================
// grid (64, B), block 256 -> 512 points per block
template <bool LAST>
__global__ __launch_bounds__(256) void assign_kernel(const float* __restrict__ xyz,
                                                     const float* __restrict__ sc,
                                                     float* __restrict__ ws,
                                                     float* __restrict__ gamma_out) {
    __shared__ float4 cLds[KK];
    __shared__ float accLds[4 * KK];
    int b = blockIdx.y, tid = threadIdx.x;
    int n0 = blockIdx.x * 512;
    const float4* cT = (const float4*)(ws + CT_OFF) + (size_t)b * KK;
    if (tid < KK) cLds[tid] = cT[tid];
    accLds[tid] = 0.f;
    accLds[tid + 256] = 0.f;
    __syncthreads();

    const float* X = xyz + (size_t)b * 3 * NN;
    int n0t = n0 + tid;
    float px0 = X[n0t],           px1 = X[n0t + 256];
    float py0 = X[NN + n0t],      py1 = X[NN + n0t + 256];
    float pz0 = X[2 * NN + n0t],  pz1 = X[2 * NN + n0t + 256];
    float s0 = sc[(size_t)b * NN + n0t], s1 = sc[(size_t)b * NN + n0t + 256];

    // pass 1: l = sum_k exp(score)   (no max-sub needed: |score| <~ 60)
    float l0 = 0.f, l1 = 0.f;
    int kk = tid & 63;
    for (int j = 0; j < KK; j++) {
        int k = (j + kk) & (KK - 1);
        float4 c = cLds[k];
        l0 += __expf(fmaf(px0, c.x, fmaf(py0, c.y, fmaf(pz0, c.z, c.w))));
        l1 += __expf(fmaf(px1, c.x, fmaf(py1, c.y, fmaf(pz1, c.z, c.w))));
    }
    float w0 = s0 / l0, w1 = s1 / l1;

    float* g0p = gamma_out + (size_t)(b * NN + n0t) * KK;
    float* g1p = g0p + (size_t)256 * KK;

    // pass 2: gamma + accumulate (staggered k -> conflict-free LDS atomics)
    for (int j = 0; j < KK; j++) {
        int k = (j + kk) & (KK - 1);
        float4 c = cLds[k];
        float e0 = __expf(fmaf(px0, c.x, fmaf(py0, c.y, fmaf(pz0, c.z, c.w)))) * w0;
        float e1 = __expf(fmaf(px1, c.x, fmaf(py1, c.y, fmaf(pz1, c.z, c.w)))) * w1;
        if (LAST) { g0p[k] = e0; g1p[k] = e1; }
        atomicAdd(&accLds[k],          fmaf(e0, px0, e1 * px1));
        atomicAdd(&accLds[KK + k],     fmaf(e0, py0, e1 * py1));
        atomicAdd(&accLds[2 * KK + k], fmaf(e0, pz0, e1 * pz1));
        atomicAdd(&accLds[3 * KK + k], e0 + e1);
    }
    __syncthreads();
    float* acc = ws + ACC_OFF + (size_t)b * KK * 4;
    for (int i = tid; i < 4 * KK; i += 256) {
        int c = i >> 7, k = i & (KK - 1);
        atomicAdd(&acc[k * 4 + c], accLds[c * KK + k]);
    }
}

// ================= center update (+ final outputs) =================
template <bool FINAL>
__global__ void update_kernel(float* __restrict__ ws, float* __restrict__ out) {
    int b = blockIdx.x, k = threadIdx.x;  // grid B, block K
    float* acc = ws + ACC_OFF + (size_t)(b * KK + k) * 4;
    float ax = acc[0], ay = acc[1], az = acc[2], aw = acc[3];
    float denom = aw + EPSV;
    float cx = ax / denom, cy = ay / denom, cz = az / denom;
    float4* cT = (float4*)(ws + CT_OFF);
    cT[b * KK + k] = make_float4(2.f * cx / TAU, 2.f * cy / TAU, 2.f * cz / TAU,
                                 -(cx * cx + cy * cy + cz * cz) / TAU);
    if (FINAL) {
        out[PI_OFF + b * KK + k] = aw / ws[SS_OFF + b];
        float* oxyz = out + XY_OFF + (size_t)(b * KK + k) * 3;
        oxyz[0] = cx; oxyz[1] = cy; oxyz[2] = cz;
        // keep acc (denom) for nf_finalize
    } else {
        acc[0] = 0.f; acc[1] = 0.f; acc[2] = 0.f; acc[3] = 0.f;
    }
}

// ================= node_feats GEMM: nf[k][d] += gamma[n][k] * f[d][n] =================
// grid (32, B), block 256; each block: 1024 points, tiles of 64
__global__ __launch_bounds__(256) void nf_gemm(const float* __restrict__ gamma,
                                               const float* __restrict__ feats,
                                               float* __restrict__ ws) {
    __shared__ float gLds[64 * 128];
    __shared__ float fLds[64 * 65];
    int b = blockIdx.y, part = blockIdx.x, tid = threadIdx.x;
    int grp = tid >> 7, tt = tid & 127;
    int k0 = (tt >> 3) * 8, d0 = (tt & 7) * 8;
    float racc[64];
    #pragma unroll
    for (int i = 0; i < 64; i++) racc[i] = 0.f;
    const float* gb = gamma + (size_t)b * NN * KK;
    const float* fb = feats + (size_t)b * DD * NN;
    int nbase = part * 1024;
    for (int t = 0; t < 16; t++) {
        int nb = nbase + t * 64;
        const float4* gsrc = (const float4*)(gb + (size_t)nb * KK);
        float4* gdst = (float4*)gLds;
        #pragma unroll
        for (int j = 0; j < 8; j++) gdst[tid + j * 256] = gsrc[tid + j * 256];
        #pragma unroll
        for (int j = 0; j < 16; j++) {
            int idx = tid + j * 256;
            int dd = idx >> 6, nl = idx & 63;
            fLds[dd * 65 + nl] = fb[(size_t)dd * NN + nb + nl];
        }
        __syncthreads();
        for (int nl = grp; nl < 64; nl += 2) {
            float4 g0 = *(const float4*)&gLds[nl * 128 + k0];
            float4 g1 = *(const float4*)&gLds[nl * 128 + k0 + 4];
            float fv[8];
            #pragma unroll
            for (int j = 0; j < 8; j++) fv[j] = fLds[(d0 + j) * 65 + nl];
            float gk[8] = {g0.x, g0.y, g0.z, g0.w, g1.x, g1.y, g1.z, g1.w};
            #pragma unroll
            for (int a = 0; a < 8; a++)
                #pragma unroll
                for (int j = 0; j < 8; j++)
                    racc[a * 8 + j] = fmaf(gk[a], fv[j], racc[a * 8 + j]);
        }
        __syncthreads();
    }
    if (grp == 1) {
        #pragma unroll
        for (int i = 0; i < 64; i++) gLds[tt * 64 + i] = racc[i];
    }
    __syncthreads();
    if (grp == 0) {
        float* nf = ws + NF_OFF + (size_t)b * KK * DD;
        #pragma unroll
        for (int a = 0; a < 8; a++)
            #pragma unroll
            for (int j = 0; j < 8; j++)
                atomicAdd(&nf[(k0 + a) * DD + d0 + j],
                          racc[a * 8 + j] + gLds[tt * 64 + a * 8 + j]);
    }
}

__global__ __launch_bounds__(256) void nf_finalize(const float* __restrict__ ws,
                                                   float* __restrict__ out) {
    int idx = blockIdx.x * 256 + threadIdx.x;  // B*K*D
    int bk = idx / DD;
    float denom = ws[ACC_OFF + bk * 4 + 3] + EPSV;
    out[NF_OUT + idx] = ws[NF_OFF + idx] / denom;
}

extern "C" void kernel_launch(void* const* d_in, const int* in_sizes, int n_in,
                              void* d_out, int out_size, void* d_ws, size_t ws_size,
                              hipStream_t stream) {
    const float* xyz = (const float*)d_in[0];
    const float* feats = (const float*)d_in[1];
    const float* sc = (const float*)d_in[2];
    float* out = (float*)d_out;
    float* ws = (float*)d_ws;

    hipMemsetAsync(ws + NF_OFF, 0, (size_t)BB * KK * DD * sizeof(float), stream);
    prep_kernel<<<BB, 256, 0, stream>>>(xyz, sc, ws);
    for (int it = 0; it < ITERS - 1; it++) {
        assign_kernel<false><<<dim3(64, BB), 256, 0, stream>>>(xyz, sc, ws, out);
        update_kernel<false><<<BB, KK, 0, stream>>>(ws, out);
    }
    assign_kernel<true><<<dim3(64, BB), 256, 0, stream>>>(xyz, sc, ws, out);
    update_kernel<true><<<BB, KK, 0, stream>>>(ws, out);
    nf_gemm<<<dim3(32, BB), 256, 0, stream>>>(out, feats, ws);
    nf_finalize<<<256, 256, 0, stream>>>(ws, out);
}

// Round 3
// 501.100 us; speedup vs baseline: 7.4226x; 7.4226x over previous
//
#include <hip/hip_runtime.h>

#define BB 8
#define NN 32768
#define KK 128
#define DD 64
#define TAU 1.0f
#define ITERS 10
#define EPSV 1e-8f

// ---- d_out layout (floats) ----
#define G_SZ   ((size_t)BB * NN * KK)
#define PI_OFF (G_SZ)
#define XY_OFF (PI_OFF + (size_t)BB * KK)
#define NF_OUT (XY_OFF + (size_t)BB * KK * 3)

// ---- d_ws layout (floats) ----
// acc slices: (ITERS+1) * B*K*4 floats. Slice it = accumulator state after
// iteration it (slice 0 = initial centers encoded as {cx,cy,cz,1.0}).
#define SLICE_F (BB * KK * 4)                  // 4096
#define SS_OFF  ((ITERS + 1) * SLICE_F)        // 45056: s_sum per batch (B)
#define WS_FLOATS (SS_OFF + 16)

// ================= prep: s_sum + initial centers as acc slice 0 =================
__global__ __launch_bounds__(256) void prep_kernel(const float* __restrict__ xyz,
                                                   const float* __restrict__ sc,
                                                   float* __restrict__ ws) {
    int b = blockIdx.x, tid = threadIdx.x, wave = tid >> 6, lane = tid & 63;
    const float* S = sc + (size_t)b * NN;
    float sum = 0.f;
    for (int i = tid; i < NN; i += 256) sum += S[i];
    #pragma unroll
    for (int m = 1; m <= 32; m <<= 1) sum += __shfl_xor(sum, m, 64);
    __shared__ float red[4];
    if (lane == 0) red[wave] = sum;
    __syncthreads();
    if (tid == 0) ws[SS_OFF + b] = red[0] + red[1] + red[2] + red[3] + EPSV;
    if (tid < KK) {
        const float* X = xyz + (size_t)b * 3 * NN;
        int i0 = tid * (NN / KK);
        ((float4*)ws)[b * KK + tid] =
            make_float4(X[i0], X[NN + i0], X[2 * NN + i0], 1.0f);
    }
}

// ================= assign: centers-from-acc prologue + softmax + accumulate ====
// grid (128, B), block 256; each block owns 256 points.
// Lane l of each wave owns clusters k=l and k=l+64 (register accumulators).
template <bool LAST>
__global__ __launch_bounds__(256) void assign_kernel(
    const float* __restrict__ xyz, const float* __restrict__ sc,
    const float4* __restrict__ accIn,   // slice it   [B][K]{ax,ay,az,aw}
    float* __restrict__ accOut,         // slice it+1 [B][K*4], pre-zeroed
    float* __restrict__ gamma_out)
{
    __shared__ float4 cLds[KK];      // transformed centers {2cx,2cy,2cz,-|c|^2}/tau
    __shared__ float4 wLds[256];     // this block's points {x,y,z,s}
    __shared__ float  accW[4][512];  // per-wave partial sums [wave][k*4+c]

    const int b = blockIdx.y, blk = blockIdx.x;
    const int tid = threadIdx.x, wave = tid >> 6, lane = tid & 63;

    const float* X = xyz + (size_t)b * 3 * NN;
    const float* S = sc + (size_t)b * NN;

    const int n = blk * 256 + tid;
    wLds[tid] = make_float4(X[n], X[NN + n], X[2 * NN + n], S[n]);

    if (tid < KK) {                    // center update from previous accumulator
        float4 a = accIn[b * KK + tid];
        float denom = a.w + EPSV;
        float cx = a.x / denom, cy = a.y / denom, cz = a.z / denom;
        cLds[tid] = make_float4(2.f * cx / TAU, 2.f * cy / TAU, 2.f * cz / TAU,
                                -(cx * cx + cy * cy + cz * cz) / TAU);
    }
    __syncthreads();

    const float4 c0 = cLds[lane];
    const float4 c1 = cLds[lane + 64];
    float ax0 = 0, ay0 = 0, az0 = 0, aw0 = 0;
    float ax1 = 0, ay1 = 0, az1 = 0, aw1 = 0;
    float* grow = gamma_out + ((size_t)b * NN + blk * 256 + (wave << 6)) * KK + lane;

    #pragma unroll 4
    for (int j = 0; j < 64; ++j) {
        float4 P = wLds[(wave << 6) | j];   // wave-uniform broadcast
        float s0 = fmaf(P.x, c0.x, fmaf(P.y, c0.y, fmaf(P.z, c0.z, c0.w)));
        float s1 = fmaf(P.x, c1.x, fmaf(P.y, c1.y, fmaf(P.z, c1.z, c1.w)));
        float e0 = __expf(s0), e1 = __expf(s1);
        float t = e0 + e1;                   // softmax denom over 64 lanes
        #pragma unroll
        for (int m = 1; m <= 32; m <<= 1) t += __shfl_xor(t, m, 64);
        float w = P.w / t;
        float g0 = e0 * w, g1 = e1 * w;
        if (LAST) {
            grow[(size_t)j * KK] = g0;       // gamma[b][n][k], 256B-coalesced/wave
            grow[(size_t)j * KK + 64] = g1;
        }
        ax0 = fmaf(g0, P.x, ax0); ay0 = fmaf(g0, P.y, ay0);
        az0 = fmaf(g0, P.z, az0); aw0 += g0;
        ax1 = fmaf(g1, P.x, ax1); ay1 = fmaf(g1, P.y, ay1);
        az1 = fmaf(g1, P.z, az1); aw1 += g1;
    }

    // intra-block reduce: plain LDS stores, 4-way sum, one global atomic per value
    ((float4*)accW[wave])[lane]      = make_float4(ax0, ay0, az0, aw0);
    ((float4*)accW[wave])[lane + 64] = make_float4(ax1, ay1, az1, aw1);
    __syncthreads();
    float v0 = accW[0][tid]       + accW[1][tid]       + accW[2][tid]       + accW[3][tid];
    float v1 = accW[0][tid + 256] + accW[1][tid + 256] + accW[2][tid + 256] + accW[3][tid + 256];
    float* ag = accOut + b * (KK * 4);
    atomicAdd(ag + tid, v0);
    atomicAdd(ag + tid + 256, v1);
}

// ================= final: node_xyz + pi from slice ITERS =================
__global__ void final_kernel(const float* __restrict__ ws, float* __restrict__ out) {
    int b = blockIdx.x, k = threadIdx.x;  // grid B, block K
    float4 a = ((const float4*)(ws + ITERS * SLICE_F))[b * KK + k];
    float denom = a.w + EPSV;
    float* oxyz = out + XY_OFF + (size_t)(b * KK + k) * 3;
    oxyz[0] = a.x / denom; oxyz[1] = a.y / denom; oxyz[2] = a.z / denom;
    out[PI_OFF + b * KK + k] = a.w / ws[SS_OFF + b];
}

// ================= node_feats GEMM: nf[k][d] += gamma[n][k] * f[d][n] ==========
__global__ __launch_bounds__(256) void nf_gemm(const float* __restrict__ gamma,
                                               const float* __restrict__ feats,
                                               float* __restrict__ nf_acc) {
    __shared__ float gLds[64 * 128];
    __shared__ float fLds[64 * 65];
    int b = blockIdx.y, part = blockIdx.x, tid = threadIdx.x;
    int grp = tid >> 7, tt = tid & 127;
    int k0 = (tt >> 3) * 8, d0 = (tt & 7) * 8;
    float racc[64];
    #pragma unroll
    for (int i = 0; i < 64; i++) racc[i] = 0.f;
    const float* gb = gamma + (size_t)b * NN * KK;
    const float* fb = feats + (size_t)b * DD * NN;
    int nbase = part * 1024;
    for (int t = 0; t < 16; t++) {
        int nb = nbase + t * 64;
        const float4* gsrc = (const float4*)(gb + (size_t)nb * KK);
        float4* gdst = (float4*)gLds;
        #pragma unroll
        for (int j = 0; j < 8; j++) gdst[tid + j * 256] = gsrc[tid + j * 256];
        #pragma unroll
        for (int j = 0; j < 16; j++) {
            int idx = tid + j * 256;
            int dd = idx >> 6, nl = idx & 63;
            fLds[dd * 65 + nl] = fb[(size_t)dd * NN + nb + nl];
        }
        __syncthreads();
        for (int nl = grp; nl < 64; nl += 2) {
            float4 g0 = *(const float4*)&gLds[nl * 128 + k0];
            float4 g1 = *(const float4*)&gLds[nl * 128 + k0 + 4];
            float fv[8];
            #pragma unroll
            for (int j = 0; j < 8; j++) fv[j] = fLds[(d0 + j) * 65 + nl];
            float gk[8] = {g0.x, g0.y, g0.z, g0.w, g1.x, g1.y, g1.z, g1.w};
            #pragma unroll
            for (int a = 0; a < 8; a++)
                #pragma unroll
                for (int j = 0; j < 8; j++)
                    racc[a * 8 + j] = fmaf(gk[a], fv[j], racc[a * 8 + j]);
        }
        __syncthreads();
    }
    if (grp == 1) {
        #pragma unroll
        for (int i = 0; i < 64; i++) gLds[tt * 64 + i] = racc[i];
    }
    __syncthreads();
    if (grp == 0) {
        float* nf = nf_acc + (size_t)b * KK * DD;
        #pragma unroll
        for (int a = 0; a < 8; a++)
            #pragma unroll
            for (int j = 0; j < 8; j++)
                atomicAdd(&nf[(k0 + a) * DD + d0 + j],
                          racc[a * 8 + j] + gLds[tt * 64 + a * 8 + j]);
    }
}

__global__ __launch_bounds__(256) void nf_finalize(const float* __restrict__ ws,
                                                   float* __restrict__ out) {
    int idx = blockIdx.x * 256 + threadIdx.x;  // B*K*D
    int bk = idx / DD;
    float denom = ws[ITERS * SLICE_F + bk * 4 + 3] + EPSV;
    out[NF_OUT + idx] = out[NF_OUT + idx] / denom;   // in-place finalize
}

extern "C" void kernel_launch(void* const* d_in, const int* in_sizes, int n_in,
                              void* d_out, int out_size, void* d_ws, size_t ws_size,
                              hipStream_t stream) {
    const float* xyz = (const float*)d_in[0];
    const float* feats = (const float*)d_in[1];
    const float* sc = (const float*)d_in[2];
    float* out = (float*)d_out;
    float* ws = (float*)d_ws;

    hipMemsetAsync(ws, 0, (size_t)WS_FLOATS * sizeof(float), stream);
    hipMemsetAsync(out + NF_OUT, 0, (size_t)BB * KK * DD * sizeof(float), stream);
    prep_kernel<<<BB, 256, 0, stream>>>(xyz, sc, ws);

    for (int it = 0; it < ITERS - 1; it++) {
        assign_kernel<false><<<dim3(128, BB), 256, 0, stream>>>(
            xyz, sc, (const float4*)(ws + it * SLICE_F),
            ws + (it + 1) * SLICE_F, out);
    }
    assign_kernel<true><<<dim3(128, BB), 256, 0, stream>>>(
        xyz, sc, (const float4*)(ws + (ITERS - 1) * SLICE_F),
        ws + ITERS * SLICE_F, out);

    final_kernel<<<BB, KK, 0, stream>>>(ws, out);
    nf_gemm<<<dim3(32, BB), 256, 0, stream>>>(out, feats, out + NF_OUT);
    nf_finalize<<<256, 256, 0, stream>>>(ws, out);
}

// Round 4
// 329.996 us; speedup vs baseline: 11.2713x; 1.5185x over previous
//
#include <hip/hip_runtime.h>

#define BB 8
#define NN 32768
#define KK 128
#define DD 64
#define TAU 1.0f
#define ITERS 10
#define EPSV 1e-8f
#define JPARTS 128

// ---- d_out layout (floats) ----
#define G_SZ   ((size_t)BB * NN * KK)
#define PI_OFF (G_SZ)
#define XY_OFF (PI_OFF + (size_t)BB * KK)
#define NF_OUT (XY_OFF + (size_t)BB * KK * 3)

// ---- d_ws layout (floats) ----
#define SLICE_F (BB * KK * 4)                  // 4096
#define SS_OFF  ((ITERS + 1) * SLICE_F)        // 45056
#define HDR_F   (SS_OFF + 16)                  // 45072 (16B-aligned)
#define PART_OFF HDR_F                         // partials: JPARTS*B*K*D
#define PART_F  ((size_t)JPARTS * BB * KK * DD)
#define WS_NEED_BYTES ((PART_OFF + PART_F) * 4)

// ================= prep: s_sum + initial centers as acc slice 0 =================
__global__ __launch_bounds__(256) void prep_kernel(const float* __restrict__ xyz,
                                                   const float* __restrict__ sc,
                                                   float* __restrict__ ws) {
    int b = blockIdx.x, tid = threadIdx.x, wave = tid >> 6, lane = tid & 63;
    const float* S = sc + (size_t)b * NN;
    float sum = 0.f;
    for (int i = tid; i < NN; i += 256) sum += S[i];
    #pragma unroll
    for (int m = 1; m <= 32; m <<= 1) sum += __shfl_xor(sum, m, 64);
    __shared__ float red[4];
    if (lane == 0) red[wave] = sum;
    __syncthreads();
    if (tid == 0) ws[SS_OFF + b] = red[0] + red[1] + red[2] + red[3] + EPSV;
    if (tid < KK) {
        const float* X = xyz + (size_t)b * 3 * NN;
        int i0 = tid * (NN / KK);
        ((float4*)ws)[b * KK + tid] =
            make_float4(X[i0], X[NN + i0], X[2 * NN + i0], 1.0f);
    }
}

// ============ assign: 2-pass softmax (pass1 lane-per-point, pass2 k-per-lane) ==
// grid (128, B), block 256; each block owns 256 points.
template <bool LAST>
__global__ __launch_bounds__(256) void assign_kernel(
    const float* __restrict__ xyz, const float* __restrict__ sc,
    const float4* __restrict__ accIn,   // slice it
    float* __restrict__ accOut,         // slice it+1 (pre-zeroed)
    float* __restrict__ gamma_out)
{
    __shared__ float4 cLds[KK];      // {2cx,2cy,2cz,-|c|^2}/tau
    __shared__ float4 wLds[256];     // {x,y,z, s/l}
    __shared__ float  accW[4][512];

    const int b = blockIdx.y, blk = blockIdx.x;
    const int tid = threadIdx.x, wave = tid >> 6, lane = tid & 63;

    const float* X = xyz + (size_t)b * 3 * NN;
    const float* S = sc + (size_t)b * NN;

    const int n = blk * 256 + tid;
    const float px = X[n], py = X[NN + n], pz = X[2 * NN + n], ps = S[n];

    if (tid < KK) {
        float4 a = accIn[b * KK + tid];
        float denom = a.w + EPSV;
        float cx = a.x / denom, cy = a.y / denom, cz = a.z / denom;
        cLds[tid] = make_float4(2.f * cx / TAU, 2.f * cy / TAU, 2.f * cz / TAU,
                                -(cx * cx + cy * cy + cz * cz) / TAU);
    }
    __syncthreads();

    // pass 1: each thread computes its own point's softmax denominator.
    // cLds[k] is wave-uniform -> broadcast reads, no shuffles anywhere.
    float l0 = 0.f, l1 = 0.f;
    #pragma unroll 8
    for (int k = 0; k < KK; k += 2) {
        float4 ca = cLds[k], cb = cLds[k + 1];
        l0 += __expf(fmaf(px, ca.x, fmaf(py, ca.y, fmaf(pz, ca.z, ca.w))));
        l1 += __expf(fmaf(px, cb.x, fmaf(py, cb.y, fmaf(pz, cb.z, cb.w))));
    }
    wLds[tid] = make_float4(px, py, pz, ps / (l0 + l1));
    __syncthreads();

    // pass 2: lane l owns clusters l and l+64; register accumulators.
    const float4 c0 = cLds[lane];
    const float4 c1 = cLds[lane + 64];
    float ax0 = 0, ay0 = 0, az0 = 0, aw0 = 0;
    float ax1 = 0, ay1 = 0, az1 = 0, aw1 = 0;
    float* grow = gamma_out + ((size_t)b * NN + blk * 256 + (wave << 6)) * KK + lane;

    #pragma unroll 4
    for (int j = 0; j < 64; ++j) {
        float4 P = wLds[(wave << 6) | j];   // wave-uniform broadcast
        float g0 = __expf(fmaf(P.x, c0.x, fmaf(P.y, c0.y, fmaf(P.z, c0.z, c0.w)))) * P.w;
        float g1 = __expf(fmaf(P.x, c1.x, fmaf(P.y, c1.y, fmaf(P.z, c1.z, c1.w)))) * P.w;
        if (LAST) {
            grow[(size_t)j * KK] = g0;
            grow[(size_t)j * KK + 64] = g1;
        }
        ax0 = fmaf(g0, P.x, ax0); ay0 = fmaf(g0, P.y, ay0);
        az0 = fmaf(g0, P.z, az0); aw0 += g0;
        ax1 = fmaf(g1, P.x, ax1); ay1 = fmaf(g1, P.y, ay1);
        az1 = fmaf(g1, P.z, az1); aw1 += g1;
    }

    ((float4*)accW[wave])[lane]      = make_float4(ax0, ay0, az0, aw0);
    ((float4*)accW[wave])[lane + 64] = make_float4(ax1, ay1, az1, aw1);
    __syncthreads();
    float v0 = accW[0][tid]       + accW[1][tid]       + accW[2][tid]       + accW[3][tid];
    float v1 = accW[0][tid + 256] + accW[1][tid + 256] + accW[2][tid + 256] + accW[3][tid + 256];
    float* ag = accOut + b * (KK * 4);
    atomicAdd(ag + tid, v0);
    atomicAdd(ag + tid + 256, v1);
}

// ================= final: node_xyz + pi from slice ITERS =================
__global__ void final_kernel(const float* __restrict__ ws, float* __restrict__ out) {
    int b = blockIdx.x, k = threadIdx.x;
    float4 a = ((const float4*)(ws + ITERS * SLICE_F))[b * KK + k];
    float denom = a.w + EPSV;
    float* oxyz = out + XY_OFF + (size_t)(b * KK + k) * 3;
    oxyz[0] = a.x / denom; oxyz[1] = a.y / denom; oxyz[2] = a.z / denom;
    out[PI_OFF + b * KK + k] = a.w / ws[SS_OFF + b];
}

// ====== nf_compute: partial nf[k][d] = sum_n gamma[n][k]*f[d][n] over n-part ===
// grid (JPARTS, B), block 256. Each block: 256 n in 8 chunks of 32.
// Thread t: clusters kq..kq+7 (kq=(t&15)*8), dims dg..dg+3 (dg=(t>>4)*4).
template <bool ATOMIC>
__global__ __launch_bounds__(256) void nf_compute(const float* __restrict__ gamma,
                                                  const float* __restrict__ feats,
                                                  float* __restrict__ dst) {
    __shared__ float gLds[32 * 128];   // 16 KB
    __shared__ float fLds[64 * 33];    // 8.25 KB, pad 33 -> d-group reads 2-way/free
    const int b = blockIdx.y, part = blockIdx.x, tid = threadIdx.x;
    const int kq = (tid & 15) * 8, dg = (tid >> 4) * 4;

    float acc[8][4];
    #pragma unroll
    for (int i = 0; i < 8; i++)
        #pragma unroll
        for (int u = 0; u < 4; u++) acc[i][u] = 0.f;

    const float* gb = gamma + (size_t)b * NN * KK + (size_t)part * (NN / JPARTS) * KK;
    const float* fb = feats + (size_t)b * DD * NN + part * (NN / JPARTS);

    for (int ch = 0; ch < (NN / JPARTS) / 32; ++ch) {
        const float4* gs = (const float4*)(gb + (size_t)ch * 32 * KK);
        #pragma unroll
        for (int i = 0; i < 4; i++) ((float4*)gLds)[tid + i * 256] = gs[tid + i * 256];
        #pragma unroll
        for (int i = 0; i < 2; i++) {
            int idx = tid + i * 256;
            int d = idx >> 3, c4 = (idx & 7) * 4;
            float4 fv = *(const float4*)(fb + (size_t)d * NN + ch * 32 + c4);
            float* fr = &fLds[d * 33 + c4];
            fr[0] = fv.x; fr[1] = fv.y; fr[2] = fv.z; fr[3] = fv.w;
        }
        __syncthreads();
        #pragma unroll 4
        for (int nl = 0; nl < 32; ++nl) {
            float4 g0 = *(const float4*)&gLds[nl * 128 + kq];
            float4 g1 = *(const float4*)&gLds[nl * 128 + kq + 4];
            float fv[4];
            #pragma unroll
            for (int u = 0; u < 4; u++) fv[u] = fLds[(dg + u) * 33 + nl];
            float gk[8] = {g0.x, g0.y, g0.z, g0.w, g1.x, g1.y, g1.z, g1.w};
            #pragma unroll
            for (int i = 0; i < 8; i++)
                #pragma unroll
                for (int u = 0; u < 4; u++)
                    acc[i][u] = fmaf(gk[i], fv[u], acc[i][u]);
        }
        __syncthreads();
    }

    if (ATOMIC) {
        float* nf = dst + (size_t)b * KK * DD;
        #pragma unroll
        for (int i = 0; i < 8; i++)
            #pragma unroll
            for (int u = 0; u < 4; u++)
                atomicAdd(&nf[(kq + i) * DD + dg + u], acc[i][u]);
    } else {
        float* p = dst + ((size_t)(b * JPARTS + part)) * (KK * DD);
        #pragma unroll
        for (int i = 0; i < 8; i++)
            *(float4*)&p[(kq + i) * DD + dg] =
                make_float4(acc[i][0], acc[i][1], acc[i][2], acc[i][3]);
    }
}

// ====== nf_reduce: sum JPARTS partials, divide by denom, write out ======
__global__ __launch_bounds__(256) void nf_reduce(const float* __restrict__ ws,
                                                 float* __restrict__ out) {
    int idx = blockIdx.x * 256 + threadIdx.x;       // [0, B*K*D)
    int b = idx >> 13, e = idx & 8191;
    const float* p = ws + PART_OFF + (size_t)b * JPARTS * (KK * DD) + e;
    float sum = 0.f;
    #pragma unroll 8
    for (int j = 0; j < JPARTS; ++j) sum += p[(size_t)j * (KK * DD)];
    int k = e >> 6;
    float denom = ws[ITERS * SLICE_F + (b * KK + k) * 4 + 3] + EPSV;
    out[NF_OUT + idx] = sum / denom;
}

__global__ __launch_bounds__(256) void nf_finalize(const float* __restrict__ ws,
                                                   float* __restrict__ out) {
    int idx = blockIdx.x * 256 + threadIdx.x;
    int bk = idx / DD;
    float denom = ws[ITERS * SLICE_F + bk * 4 + 3] + EPSV;
    out[NF_OUT + idx] = out[NF_OUT + idx] / denom;
}

extern "C" void kernel_launch(void* const* d_in, const int* in_sizes, int n_in,
                              void* d_out, int out_size, void* d_ws, size_t ws_size,
                              hipStream_t stream) {
    const float* xyz = (const float*)d_in[0];
    const float* feats = (const float*)d_in[1];
    const float* sc = (const float*)d_in[2];
    float* out = (float*)d_out;
    float* ws = (float*)d_ws;

    hipMemsetAsync(ws, 0, (size_t)HDR_F * sizeof(float), stream);
    prep_kernel<<<BB, 256, 0, stream>>>(xyz, sc, ws);

    for (int it = 0; it < ITERS - 1; it++) {
        assign_kernel<false><<<dim3(128, BB), 256, 0, stream>>>(
            xyz, sc, (const float4*)(ws + it * SLICE_F),
            ws + (it + 1) * SLICE_F, out);
    }
    assign_kernel<true><<<dim3(128, BB), 256, 0, stream>>>(
        xyz, sc, (const float4*)(ws + (ITERS - 1) * SLICE_F),
        ws + ITERS * SLICE_F, out);

    final_kernel<<<BB, KK, 0, stream>>>(ws, out);

    if (ws_size >= WS_NEED_BYTES) {
        nf_compute<false><<<dim3(JPARTS, BB), 256, 0, stream>>>(out, feats, ws + PART_OFF);
        nf_reduce<<<256, 256, 0, stream>>>(ws, out);
    } else {
        hipMemsetAsync(out + NF_OUT, 0, (size_t)BB * KK * DD * sizeof(float), stream);
        nf_compute<true><<<dim3(JPARTS, BB), 256, 0, stream>>>(out, feats, out + NF_OUT);
        nf_finalize<<<256, 256, 0, stream>>>(ws, out);
    }
}